// Round 1
// baseline (22437.709 us; speedup 1.0000x reference)
//
#include <hip/hip_runtime.h>

#define NN 100000
#define NE 3200000

// ---------------------------------------------------------------------------
// GEMM: C[M][N] = A[M][K] * B[K][N]; BM=BN=64, BK=16, 256 threads, 4x4 microtile
// ---------------------------------------------------------------------------
__global__ __launch_bounds__(256) void gemm64(const float* __restrict__ A,
                                              const float* __restrict__ B,
                                              float* __restrict__ C,
                                              int M, int N, int K) {
    __shared__ float As[16][64];   // stored transposed: As[k][m]
    __shared__ float Bs[16][64];   // Bs[k][n]

    const int t    = threadIdx.x;
    const int brow = blockIdx.x * 64;
    const int bcol = blockIdx.y * 64;
    const int tm = t >> 4, tn = t & 15;          // 16x16 thread grid
    const int ar = t >> 2, ac = (t & 3) << 2;    // A-load: row 0..63, col4
    const int br = t >> 4, bc = (t & 15) << 2;   // B-load: row 0..15, col4

    const bool arow_ok = (brow + ar) < M;
    const float* Aptr = A + (size_t)(brow + ar) * K + ac;
    const float* Bptr = B + (size_t)br * N + bcol + bc;

    float acc[4][4] = {};

    for (int k0 = 0; k0 < K; k0 += 16) {
        float4 av = arow_ok ? *(const float4*)(Aptr + k0)
                            : make_float4(0.f, 0.f, 0.f, 0.f);
        float4 bv = *(const float4*)(Bptr + (size_t)k0 * N);

        As[ac + 0][ar] = av.x;
        As[ac + 1][ar] = av.y;
        As[ac + 2][ar] = av.z;
        As[ac + 3][ar] = av.w;
        *(float4*)&Bs[br][bc] = bv;
        __syncthreads();

#pragma unroll
        for (int k = 0; k < 16; ++k) {
            float4 a4 = *(const float4*)&As[k][tm << 2];
            float4 b4 = *(const float4*)&Bs[k][tn << 2];
            float a[4] = {a4.x, a4.y, a4.z, a4.w};
            float b[4] = {b4.x, b4.y, b4.z, b4.w};
#pragma unroll
            for (int i = 0; i < 4; ++i)
#pragma unroll
                for (int j = 0; j < 4; ++j) acc[i][j] += a[i] * b[j];
        }
        __syncthreads();
    }

#pragma unroll
    for (int i = 0; i < 4; ++i) {
        int row = brow + (tm << 2) + i;
        if (row < M) {
            float4 v = make_float4(acc[i][0], acc[i][1], acc[i][2], acc[i][3]);
            *(float4*)(C + (size_t)row * N + bcol + (tn << 2)) = v;
        }
    }
}

// ---------------------------------------------------------------------------
// GEMM for layer 3: C[M][16] = A[M][256] * B[256][16]; 16 rows/block
// ---------------------------------------------------------------------------
__global__ __launch_bounds__(256) void gemm_n16(const float* __restrict__ A,
                                                const float* __restrict__ B,
                                                float* __restrict__ C, int M) {
    __shared__ float As[16][260];   // +4 pad: breaks 4-way bank conflict on As[r][k]
    __shared__ float Bs[256][16];

    const int t = threadIdx.x;
    const int block_row = blockIdx.x * 16;

    // load B (256x16 = 1024 float4)
    for (int i = t; i < 1024; i += 256)
        ((float4*)&Bs[0][0])[i] = ((const float4*)B)[i];
    // load 16 rows of A (16x256 = 1024 float4)
    for (int i = t; i < 1024; i += 256) {
        int idx = i << 2;
        int r = idx >> 8, c = idx & 255;
        int row = block_row + r;
        float4 v = (row < M) ? ((const float4*)(A + (size_t)row * 256))[c >> 2]
                             : make_float4(0.f, 0.f, 0.f, 0.f);
        *(float4*)&As[r][c] = v;   // row stride 260*4=1040B = 65*16 -> 16B aligned
    }
    __syncthreads();

    const int r = t >> 4, c = t & 15;
    float acc = 0.f;
#pragma unroll 8
    for (int k = 0; k < 256; ++k) acc += As[r][k] * Bs[k][c];

    int row = block_row + r;
    if (row < M) C[(size_t)row * 16 + c] = acc;
}

// ---------------------------------------------------------------------------
// Scatter-add, 256-wide features: one wave (64 lanes x float4) per edge
// ---------------------------------------------------------------------------
__global__ __launch_bounds__(256) void scatter256(const float* __restrict__ h,
                                                  const int* __restrict__ src,
                                                  const int* __restrict__ dst,
                                                  float* __restrict__ agg) {
    const long long gid = (long long)blockIdx.x * 256 + threadIdx.x;
    const int e = (int)(gid >> 6);
    const int lane = (int)(gid & 63);
    if (e >= NE) return;
    const int s = src[e];
    const int d = dst[e];
    float4 v = ((const float4*)(h + (size_t)s * 256))[lane];
    float* ap = agg + (size_t)d * 256 + lane * 4;
    unsafeAtomicAdd(ap + 0, v.x);
    unsafeAtomicAdd(ap + 1, v.y);
    unsafeAtomicAdd(ap + 2, v.z);
    unsafeAtomicAdd(ap + 3, v.w);
}

// ---------------------------------------------------------------------------
// Scatter-add, 16-wide features: 4 lanes (x float4) per edge
// ---------------------------------------------------------------------------
__global__ __launch_bounds__(256) void scatter16(const float* __restrict__ h,
                                                 const int* __restrict__ src,
                                                 const int* __restrict__ dst,
                                                 float* __restrict__ agg) {
    const long long gid = (long long)blockIdx.x * 256 + threadIdx.x;
    const int e = (int)(gid >> 2);
    const int q = (int)(gid & 3);
    if (e >= NE) return;
    const int s = src[e];
    const int d = dst[e];
    float4 v = ((const float4*)(h + (size_t)s * 16))[q];
    float* ap = agg + (size_t)d * 16 + q * 4;
    unsafeAtomicAdd(ap + 0, v.x);
    unsafeAtomicAdd(ap + 1, v.y);
    unsafeAtomicAdd(ap + 2, v.z);
    unsafeAtomicAdd(ap + 3, v.w);
}

// ---------------------------------------------------------------------------
extern "C" void kernel_launch(void* const* d_in, const int* in_sizes, int n_in,
                              void* d_out, int out_size, void* d_ws, size_t ws_size,
                              hipStream_t stream) {
    const float* X   = (const float*)d_in[0];   // [100000, 512]
    const int*   src = (const int*)d_in[1];     // [3200000]
    const int*   dst = (const int*)d_in[2];     // [3200000]
    const float* W1  = (const float*)d_in[3];   // [512, 256]
    const float* W2  = (const float*)d_in[4];   // [256, 256]
    const float* W3  = (const float*)d_in[5];   // [256, 16]
    float* out = (float*)d_out;                 // [100000, 16]

    float* H = (float*)d_ws;                    // [NN, 256] projection buffer
    float* G = H + (size_t)NN * 256;            // [NN, 256] aggregation buffer
    const size_t buf_bytes = (size_t)NN * 256 * sizeof(float);  // 102.4 MB

    const dim3 gemm_grid((NN + 63) / 64, 4);
    const int scatter256_blocks = (int)(((long long)NE * 64) / 256);  // 800000
    const int scatter16_blocks  = (int)(((long long)NE * 4) / 256);   // 50000

    // ---- Layer 1: H = X @ W1 ; G = segment_sum(H[src], dst) ----
    gemm64<<<gemm_grid, 256, 0, stream>>>(X, W1, H, NN, 256, 512);
    hipMemsetAsync(G, 0, buf_bytes, stream);
    scatter256<<<scatter256_blocks, 256, 0, stream>>>(H, src, dst, G);

    // ---- Layer 2: H = G @ W2 ; G = segment_sum(H[src], dst) ----
    gemm64<<<gemm_grid, 256, 0, stream>>>(G, W2, H, NN, 256, 256);
    hipMemsetAsync(G, 0, buf_bytes, stream);   // safe: gemm64 drained G first (stream order)
    scatter256<<<scatter256_blocks, 256, 0, stream>>>(H, src, dst, G);

    // ---- Layer 3: H3 = G @ W3 ; out = segment_sum(H3[src], dst) ----
    float* H3 = H;  // reuse, only [NN,16] needed
    gemm_n16<<<(NN + 15) / 16, 256, 0, stream>>>(G, W3, H3, NN);
    hipMemsetAsync(out, 0, (size_t)NN * 16 * sizeof(float), stream);
    scatter16<<<scatter16_blocks, 256, 0, stream>>>(H3, src, dst, out);
}

// Round 2
// 1882.644 us; speedup vs baseline: 11.9182x; 11.9182x over previous
//
#include <hip/hip_runtime.h>

#define NN 100000
#define NE 3200000
#define NCHUNK 98   // ceil(NN/1024)

// ===========================================================================
// GEMMs (unchanged from round 1)
// ===========================================================================
__global__ __launch_bounds__(256) void gemm64(const float* __restrict__ A,
                                              const float* __restrict__ B,
                                              float* __restrict__ C,
                                              int M, int N, int K) {
    __shared__ float As[16][64];   // As[k][m]
    __shared__ float Bs[16][64];   // Bs[k][n]

    const int t    = threadIdx.x;
    const int brow = blockIdx.x * 64;
    const int bcol = blockIdx.y * 64;
    const int tm = t >> 4, tn = t & 15;
    const int ar = t >> 2, ac = (t & 3) << 2;
    const int br = t >> 4, bc = (t & 15) << 2;

    const bool arow_ok = (brow + ar) < M;
    const float* Aptr = A + (size_t)(brow + ar) * K + ac;
    const float* Bptr = B + (size_t)br * N + bcol + bc;

    float acc[4][4] = {};

    for (int k0 = 0; k0 < K; k0 += 16) {
        float4 av = arow_ok ? *(const float4*)(Aptr + k0)
                            : make_float4(0.f, 0.f, 0.f, 0.f);
        float4 bv = *(const float4*)(Bptr + (size_t)k0 * N);

        As[ac + 0][ar] = av.x;
        As[ac + 1][ar] = av.y;
        As[ac + 2][ar] = av.z;
        As[ac + 3][ar] = av.w;
        *(float4*)&Bs[br][bc] = bv;
        __syncthreads();

#pragma unroll
        for (int k = 0; k < 16; ++k) {
            float4 a4 = *(const float4*)&As[k][tm << 2];
            float4 b4 = *(const float4*)&Bs[k][tn << 2];
            float a[4] = {a4.x, a4.y, a4.z, a4.w};
            float b[4] = {b4.x, b4.y, b4.z, b4.w};
#pragma unroll
            for (int i = 0; i < 4; ++i)
#pragma unroll
                for (int j = 0; j < 4; ++j) acc[i][j] += a[i] * b[j];
        }
        __syncthreads();
    }

#pragma unroll
    for (int i = 0; i < 4; ++i) {
        int row = brow + (tm << 2) + i;
        if (row < M) {
            float4 v = make_float4(acc[i][0], acc[i][1], acc[i][2], acc[i][3]);
            *(float4*)(C + (size_t)row * N + bcol + (tn << 2)) = v;
        }
    }
}

__global__ __launch_bounds__(256) void gemm_n16(const float* __restrict__ A,
                                                const float* __restrict__ B,
                                                float* __restrict__ C, int M) {
    __shared__ float As[16][260];
    __shared__ float Bs[256][16];

    const int t = threadIdx.x;
    const int block_row = blockIdx.x * 16;

    for (int i = t; i < 1024; i += 256)
        ((float4*)&Bs[0][0])[i] = ((const float4*)B)[i];
    for (int i = t; i < 1024; i += 256) {
        int idx = i << 2;
        int r = idx >> 8, c = idx & 255;
        int row = block_row + r;
        float4 v = (row < M) ? ((const float4*)(A + (size_t)row * 256))[c >> 2]
                             : make_float4(0.f, 0.f, 0.f, 0.f);
        *(float4*)&As[r][c] = v;
    }
    __syncthreads();

    const int r = t >> 4, c = t & 15;
    float acc = 0.f;
#pragma unroll 8
    for (int k = 0; k < 256; ++k) acc += As[r][k] * Bs[k][c];

    int row = block_row + r;
    if (row < M) C[(size_t)row * 16 + c] = acc;
}

// ===========================================================================
// CSR build: in-degree histogram -> exclusive scan -> bucket src ids by dst
// ===========================================================================
__global__ __launch_bounds__(256) void csr_hist(const int* __restrict__ dst,
                                                int* __restrict__ cnt) {
    int e = blockIdx.x * 256 + threadIdx.x;
    if (e < NE) atomicAdd(&cnt[dst[e]], 1);
}

// pass1: per-1024-chunk sums
__global__ __launch_bounds__(256) void scan_pass1(const int* __restrict__ cnt,
                                                  int* __restrict__ partials) {
    __shared__ int red[256];
    int b = blockIdx.x, t = threadIdx.x;
    int idx = b * 1024 + t * 4;
    int s = 0;
#pragma unroll
    for (int i = 0; i < 4; ++i)
        if (idx + i < NN) s += cnt[idx + i];
    red[t] = s;
    __syncthreads();
    for (int off = 128; off > 0; off >>= 1) {
        if (t < off) red[t] += red[t + off];
        __syncthreads();
    }
    if (t == 0) partials[b] = red[0];
}

// pass2: serial exclusive scan of NCHUNK partials (tiny)
__global__ void scan_pass2(int* partials) {
    if (blockIdx.x == 0 && threadIdx.x == 0) {
        int acc = 0;
        for (int i = 0; i < NCHUNK; ++i) {
            int v = partials[i];
            partials[i] = acc;
            acc += v;
        }
    }
}

// pass3: per-chunk exclusive scan + chunk base -> offs; offs[NN] = NE
__global__ __launch_bounds__(256) void scan_pass3(const int* __restrict__ cnt,
                                                  const int* __restrict__ chunk_pfx,
                                                  int* __restrict__ offs) {
    __shared__ int ts[256];
    int b = blockIdx.x, t = threadIdx.x;
    int base_idx = b * 1024 + t * 4;
    int c[4];
#pragma unroll
    for (int i = 0; i < 4; ++i) {
        int idx = base_idx + i;
        c[i] = (idx < NN) ? cnt[idx] : 0;
    }
    int s = c[0] + c[1] + c[2] + c[3];
    ts[t] = s;
    __syncthreads();
    // Hillis-Steele inclusive scan over thread sums
    for (int off = 1; off < 256; off <<= 1) {
        int v = (t >= off) ? ts[t - off] : 0;
        __syncthreads();
        ts[t] += v;
        __syncthreads();
    }
    int run = chunk_pfx[b] + (ts[t] - s);
#pragma unroll
    for (int i = 0; i < 4; ++i) {
        int idx = base_idx + i;
        if (idx < NN) offs[idx] = run;
        run += c[i];
    }
    if (b == 0 && t == 0) offs[NN] = NE;
}

__global__ __launch_bounds__(256) void csr_fill(const int* __restrict__ src,
                                                const int* __restrict__ dst,
                                                const int* __restrict__ offs,
                                                int* __restrict__ cursor,
                                                int* __restrict__ srcs) {
    int e = blockIdx.x * 256 + threadIdx.x;
    if (e >= NE) return;
    int d = dst[e];
    int pos = offs[d] + atomicAdd(&cursor[d], 1);
    srcs[pos] = src[e];
}

// ===========================================================================
// Gather-based aggregation (no atomics, no pre-zero needed)
// ===========================================================================
// 256-wide: one wave per node, lane i owns float4 column i
__global__ __launch_bounds__(256) void agg256(const float* __restrict__ h,
                                              const int* __restrict__ offs,
                                              const int* __restrict__ srcs,
                                              float* __restrict__ outp) {
    int node = blockIdx.x * 4 + (threadIdx.x >> 6);
    int lane = threadIdx.x & 63;
    if (node >= NN) return;
    int beg = offs[node], end = offs[node + 1];
    float ax = 0, ay = 0, az = 0, aw = 0;
    float bx = 0, by = 0, bz = 0, bw = 0;
    int j = beg;
    for (; j + 2 <= end; j += 2) {
        int s0 = srcs[j], s1 = srcs[j + 1];
        float4 v0 = ((const float4*)(h + (size_t)s0 * 256))[lane];
        float4 v1 = ((const float4*)(h + (size_t)s1 * 256))[lane];
        ax += v0.x; ay += v0.y; az += v0.z; aw += v0.w;
        bx += v1.x; by += v1.y; bz += v1.z; bw += v1.w;
    }
    if (j < end) {
        float4 v = ((const float4*)(h + (size_t)srcs[j] * 256))[lane];
        ax += v.x; ay += v.y; az += v.z; aw += v.w;
    }
    float4 r = make_float4(ax + bx, ay + by, az + bz, aw + bw);
    ((float4*)(outp + (size_t)node * 256))[lane] = r;
}

// 16-wide: 16 threads per node
__global__ __launch_bounds__(256) void agg16(const float* __restrict__ h,
                                             const int* __restrict__ offs,
                                             const int* __restrict__ srcs,
                                             float* __restrict__ outp) {
    int tid = blockIdx.x * 256 + threadIdx.x;
    int node = tid >> 4, f = tid & 15;
    if (node >= NN) return;
    int beg = offs[node], end = offs[node + 1];
    float acc = 0.f;
    for (int j = beg; j < end; ++j)
        acc += h[(size_t)srcs[j] * 16 + f];
    outp[(size_t)node * 16 + f] = acc;
}

// ===========================================================================
// Fallback atomic scatter (round-1 path, used only if ws too small)
// ===========================================================================
__global__ __launch_bounds__(256) void scatter256(const float* __restrict__ h,
                                                  const int* __restrict__ src,
                                                  const int* __restrict__ dst,
                                                  float* __restrict__ agg) {
    const long long gid = (long long)blockIdx.x * 256 + threadIdx.x;
    const int e = (int)(gid >> 6);
    const int lane = (int)(gid & 63);
    if (e >= NE) return;
    const int s = src[e];
    const int d = dst[e];
    float4 v = ((const float4*)(h + (size_t)s * 256))[lane];
    float* ap = agg + (size_t)d * 256 + lane * 4;
    unsafeAtomicAdd(ap + 0, v.x);
    unsafeAtomicAdd(ap + 1, v.y);
    unsafeAtomicAdd(ap + 2, v.z);
    unsafeAtomicAdd(ap + 3, v.w);
}

__global__ __launch_bounds__(256) void scatter16(const float* __restrict__ h,
                                                 const int* __restrict__ src,
                                                 const int* __restrict__ dst,
                                                 float* __restrict__ agg) {
    const long long gid = (long long)blockIdx.x * 256 + threadIdx.x;
    const int e = (int)(gid >> 2);
    const int q = (int)(gid & 3);
    if (e >= NE) return;
    const int s = src[e];
    const int d = dst[e];
    float4 v = ((const float4*)(h + (size_t)s * 16))[q];
    float* ap = agg + (size_t)d * 16 + q * 4;
    unsafeAtomicAdd(ap + 0, v.x);
    unsafeAtomicAdd(ap + 1, v.y);
    unsafeAtomicAdd(ap + 2, v.z);
    unsafeAtomicAdd(ap + 3, v.w);
}

// ===========================================================================
extern "C" void kernel_launch(void* const* d_in, const int* in_sizes, int n_in,
                              void* d_out, int out_size, void* d_ws, size_t ws_size,
                              hipStream_t stream) {
    const float* X   = (const float*)d_in[0];   // [100000, 512]
    const int*   src = (const int*)d_in[1];     // [3200000]
    const int*   dst = (const int*)d_in[2];     // [3200000]
    const float* W1  = (const float*)d_in[3];   // [512, 256]
    const float* W2  = (const float*)d_in[4];   // [256, 256]
    const float* W3  = (const float*)d_in[5];   // [256, 16]
    float* out = (float*)d_out;                 // [100000, 16]

    const size_t buf_elems = (size_t)NN * 256;
    const size_t buf_bytes = buf_elems * sizeof(float);          // 102.4 MB

    char* ws = (char*)d_ws;
    float* H = (float*)ws;                 ws += buf_bytes;
    float* G = (float*)ws;                 ws += buf_bytes;
    int* srcs     = (int*)ws;              ws += (size_t)NE * 4;          // 12.8 MB
    int* offs     = (int*)ws;              ws += ((size_t)NN + 4) * 4;    // 400 KB
    int* cnt      = (int*)ws;              ws += (size_t)NN * 4;          // 400 KB
    int* partials = (int*)ws;              ws += 512;
    const size_t need = (size_t)(ws - (char*)d_ws);

    const dim3 gemm_grid((NN + 63) / 64, 4);
    const int edge_blocks = (NE + 255) / 256;                    // 12500

    if (ws_size >= need) {
        // ---- Build CSR (once per call; same edges feed all 3 layers) ----
        hipMemsetAsync(cnt, 0, (size_t)NN * 4, stream);
        csr_hist<<<edge_blocks, 256, 0, stream>>>(dst, cnt);
        scan_pass1<<<NCHUNK, 256, 0, stream>>>(cnt, partials);
        scan_pass2<<<1, 64, 0, stream>>>(partials);
        scan_pass3<<<NCHUNK, 256, 0, stream>>>(cnt, partials, offs);
        hipMemsetAsync(cnt, 0, (size_t)NN * 4, stream);
        csr_fill<<<edge_blocks, 256, 0, stream>>>(src, dst, offs, cnt, srcs);

        // ---- Layer 1 ----
        gemm64<<<gemm_grid, 256, 0, stream>>>(X, W1, H, NN, 256, 512);
        agg256<<<NN / 4, 256, 0, stream>>>(H, offs, srcs, G);
        // ---- Layer 2 ----
        gemm64<<<gemm_grid, 256, 0, stream>>>(G, W2, H, NN, 256, 256);
        agg256<<<NN / 4, 256, 0, stream>>>(H, offs, srcs, G);
        // ---- Layer 3 ----
        float* H3 = H;
        gemm_n16<<<(NN + 15) / 16, 256, 0, stream>>>(G, W3, H3, NN);
        agg16<<<(NN * 16 + 255) / 256, 256, 0, stream>>>(H3, offs, srcs, out);
    } else {
        // ---- Fallback: round-1 atomic path (needs only 2 buffers) ----
        const int scatter256_blocks = (int)(((long long)NE * 64) / 256);
        const int scatter16_blocks  = (int)(((long long)NE * 4) / 256);

        gemm64<<<gemm_grid, 256, 0, stream>>>(X, W1, H, NN, 256, 512);
        hipMemsetAsync(G, 0, buf_bytes, stream);
        scatter256<<<scatter256_blocks, 256, 0, stream>>>(H, src, dst, G);

        gemm64<<<gemm_grid, 256, 0, stream>>>(G, W2, H, NN, 256, 256);
        hipMemsetAsync(G, 0, buf_bytes, stream);
        scatter256<<<scatter256_blocks, 256, 0, stream>>>(H, src, dst, G);

        float* H3 = H;
        gemm_n16<<<(NN + 15) / 16, 256, 0, stream>>>(G, W3, H3, NN);
        hipMemsetAsync(out, 0, (size_t)NN * 16 * sizeof(float), stream);
        scatter16<<<scatter16_blocks, 256, 0, stream>>>(H3, src, dst, out);
    }
}

// Round 3
// 1032.645 us; speedup vs baseline: 21.7284x; 1.8231x over previous
//
#include <hip/hip_runtime.h>

#define NN 100000
#define NE 3200000
#define NCHUNK 98   // ceil(NN/1024)

typedef short bf16x8 __attribute__((ext_vector_type(8)));
typedef float f32x4  __attribute__((ext_vector_type(4)));

__device__ inline unsigned rne_bf16(float x) {
    unsigned u = __float_as_uint(x);
    return (u + 0x7fffu + ((u >> 16) & 1u)) >> 16;   // round-to-nearest-even
}
__device__ inline float bflo(unsigned u) { return __uint_as_float(u << 16); }
__device__ inline float bfhi(unsigned u) { return __uint_as_float(u & 0xffff0000u); }

// ===========================================================================
// Transpose+convert W [K][256] fp32 -> Wt [256][K] bf16
// ===========================================================================
__global__ __launch_bounds__(256) void cvtW(const float* __restrict__ W,
                                            unsigned short* __restrict__ Wt, int K) {
    int idx = blockIdx.x * 256 + threadIdx.x;
    if (idx < K * 256) {
        int k = idx >> 8, n = idx & 255;
        Wt[n * K + k] = (unsigned short)rne_bf16(W[idx]);
    }
}

// ===========================================================================
// MFMA GEMM: C_bf16[M][256] = A[M][K] * Wt^T, Wt is [256][K] bf16 row-major.
// BM=128, BN=256, BK=64, 8 waves (512 thr), wave tile 64x64 (4x4 frags 16x16x32)
// A is fp32 (converted in staging) or bf16 per template flag.
// ===========================================================================
template<int K, bool A_F32>
__global__ __launch_bounds__(512) void gemm_mfma(const void* __restrict__ Av,
                                                 const unsigned short* __restrict__ Bt,
                                                 unsigned short* __restrict__ C) {
    __shared__ unsigned short As[128][72];   // row stride 144B: frag reads 2-way (free)
    __shared__ unsigned short Bs[256][72];

    const int t = threadIdx.x;
    const int brow = blockIdx.x * 128;
    const int w = t >> 6, lane = t & 63;
    const int wr = w >> 2, wc = w & 3;            // 2x4 wave grid
    const int lrow = lane & 15, lk8 = (lane >> 4) * 8;

    // staging assignment: row-per-lane (consecutive lanes -> consecutive rows)
    const int s_arow = t & 127, s_aq = t >> 7;    // A: 4 chunks of 16 halfs per row
    const int s_brow = t & 255, s_bh = t >> 8;    // B: 2 chunks of 32 halfs per row
    const bool arow_ok = (brow + s_arow) < NN;

    f32x4 acc[4][4] = {};

    for (int k0 = 0; k0 < K; k0 += 64) {
        // ---- stage A tile [128][64] ----
        if constexpr (A_F32) {
            const float* Ap = (const float*)Av + (size_t)(brow + s_arow) * K + k0 + s_aq * 16;
            float4 f[4];
            if (arow_ok) {
#pragma unroll
                for (int i = 0; i < 4; ++i) f[i] = ((const float4*)Ap)[i];
            } else {
#pragma unroll
                for (int i = 0; i < 4; ++i) f[i] = make_float4(0.f, 0.f, 0.f, 0.f);
            }
            unsigned p[8];
#pragma unroll
            for (int i = 0; i < 4; ++i) {
                p[2 * i]     = rne_bf16(f[i].x) | (rne_bf16(f[i].y) << 16);
                p[2 * i + 1] = rne_bf16(f[i].z) | (rne_bf16(f[i].w) << 16);
            }
            *(uint4*)&As[s_arow][s_aq * 16]     = make_uint4(p[0], p[1], p[2], p[3]);
            *(uint4*)&As[s_arow][s_aq * 16 + 8] = make_uint4(p[4], p[5], p[6], p[7]);
        } else {
            const unsigned short* Ap = (const unsigned short*)Av + (size_t)(brow + s_arow) * K + k0 + s_aq * 16;
            uint4 u0, u1;
            if (arow_ok) { u0 = ((const uint4*)Ap)[0]; u1 = ((const uint4*)Ap)[1]; }
            else { u0 = make_uint4(0, 0, 0, 0); u1 = u0; }
            *(uint4*)&As[s_arow][s_aq * 16]     = u0;
            *(uint4*)&As[s_arow][s_aq * 16 + 8] = u1;
        }
        // ---- stage B tile [256][64] from Wt ----
        {
            const unsigned short* Bp = Bt + (size_t)s_brow * K + k0 + s_bh * 32;
#pragma unroll
            for (int i = 0; i < 4; ++i)
                *(uint4*)&Bs[s_brow][s_bh * 32 + i * 8] = ((const uint4*)Bp)[i];
        }
        __syncthreads();

#pragma unroll
        for (int ks = 0; ks < 2; ++ks) {
            bf16x8 af[4], bb[4];
#pragma unroll
            for (int i = 0; i < 4; ++i)
                af[i] = *(const bf16x8*)&As[wr * 64 + i * 16 + lrow][ks * 32 + lk8];
#pragma unroll
            for (int n = 0; n < 4; ++n)
                bb[n] = *(const bf16x8*)&Bs[wc * 64 + n * 16 + lrow][ks * 32 + lk8];
#pragma unroll
            for (int i = 0; i < 4; ++i)
#pragma unroll
                for (int n = 0; n < 4; ++n)
                    acc[i][n] = __builtin_amdgcn_mfma_f32_16x16x32_bf16(af[i], bb[n], acc[i][n], 0, 0, 0);
        }
        __syncthreads();
    }

    // ---- epilogue: C/D layout col=lane&15, row=(lane>>4)*4+reg ----
#pragma unroll
    for (int i = 0; i < 4; ++i) {
        int rbase = brow + wr * 64 + i * 16 + (lane >> 4) * 4;
#pragma unroll
        for (int r = 0; r < 4; ++r) {
            int row = rbase + r;
            if (row < NN) {
#pragma unroll
                for (int n = 0; n < 4; ++n)
                    C[(size_t)row * 256 + wc * 64 + n * 16 + lrow] =
                        (unsigned short)rne_bf16(acc[i][n][r]);
            }
        }
    }
}

// ===========================================================================
// Layer-3 GEMM: C_f32[M][16] = A_bf16[M][256] * B_f32[256][16]
// ===========================================================================
__global__ __launch_bounds__(256) void gemm_n16b(const unsigned short* __restrict__ A,
                                                 const float* __restrict__ B,
                                                 float* __restrict__ C, int M) {
    __shared__ float As[16][260];
    __shared__ float Bs[256][16];

    const int t = threadIdx.x;
    const int block_row = blockIdx.x * 16;

    for (int i = t; i < 1024; i += 256)
        ((float4*)&Bs[0][0])[i] = ((const float4*)B)[i];
    {
        int r = t >> 4, cb = (t & 15) * 16;
        int row = block_row + r;
        uint4 u0, u1;
        if (row < M) {
            const uint4* p = (const uint4*)(A + (size_t)row * 256 + cb);
            u0 = p[0]; u1 = p[1];
        } else { u0 = make_uint4(0, 0, 0, 0); u1 = u0; }
        unsigned uu[8] = {u0.x, u0.y, u0.z, u0.w, u1.x, u1.y, u1.z, u1.w};
#pragma unroll
        for (int i = 0; i < 8; ++i) {
            As[r][cb + 2 * i]     = bflo(uu[i]);
            As[r][cb + 2 * i + 1] = bfhi(uu[i]);
        }
    }
    __syncthreads();

    const int r = t >> 4, c = t & 15;
    float acc = 0.f;
#pragma unroll 8
    for (int k = 0; k < 256; ++k) acc += As[r][k] * Bs[k][c];

    int row = block_row + r;
    if (row < M) C[(size_t)row * 16 + c] = acc;
}

// ===========================================================================
// CSR build (unchanged from round 2)
// ===========================================================================
__global__ __launch_bounds__(256) void csr_hist(const int* __restrict__ dst,
                                                int* __restrict__ cnt) {
    int e = blockIdx.x * 256 + threadIdx.x;
    if (e < NE) atomicAdd(&cnt[dst[e]], 1);
}

__global__ __launch_bounds__(256) void scan_pass1(const int* __restrict__ cnt,
                                                  int* __restrict__ partials) {
    __shared__ int red[256];
    int b = blockIdx.x, t = threadIdx.x;
    int idx = b * 1024 + t * 4;
    int s = 0;
#pragma unroll
    for (int i = 0; i < 4; ++i)
        if (idx + i < NN) s += cnt[idx + i];
    red[t] = s;
    __syncthreads();
    for (int off = 128; off > 0; off >>= 1) {
        if (t < off) red[t] += red[t + off];
        __syncthreads();
    }
    if (t == 0) partials[b] = red[0];
}

__global__ void scan_pass2(int* partials) {
    if (blockIdx.x == 0 && threadIdx.x == 0) {
        int acc = 0;
        for (int i = 0; i < NCHUNK; ++i) {
            int v = partials[i];
            partials[i] = acc;
            acc += v;
        }
    }
}

__global__ __launch_bounds__(256) void scan_pass3(const int* __restrict__ cnt,
                                                  const int* __restrict__ chunk_pfx,
                                                  int* __restrict__ offs) {
    __shared__ int ts[256];
    int b = blockIdx.x, t = threadIdx.x;
    int base_idx = b * 1024 + t * 4;
    int c[4];
#pragma unroll
    for (int i = 0; i < 4; ++i) {
        int idx = base_idx + i;
        c[i] = (idx < NN) ? cnt[idx] : 0;
    }
    int s = c[0] + c[1] + c[2] + c[3];
    ts[t] = s;
    __syncthreads();
    for (int off = 1; off < 256; off <<= 1) {
        int v = (t >= off) ? ts[t - off] : 0;
        __syncthreads();
        ts[t] += v;
        __syncthreads();
    }
    int run = chunk_pfx[b] + (ts[t] - s);
#pragma unroll
    for (int i = 0; i < 4; ++i) {
        int idx = base_idx + i;
        if (idx < NN) offs[idx] = run;
        run += c[i];
    }
    if (b == 0 && t == 0) offs[NN] = NE;
}

__global__ __launch_bounds__(256) void csr_fill(const int* __restrict__ src,
                                                const int* __restrict__ dst,
                                                const int* __restrict__ offs,
                                                int* __restrict__ cursor,
                                                int* __restrict__ srcs) {
    int e = blockIdx.x * 256 + threadIdx.x;
    if (e >= NE) return;
    int d = dst[e];
    int pos = offs[d] + atomicAdd(&cursor[d], 1);
    srcs[pos] = src[e];
}

// ===========================================================================
// Aggregation: bf16 gather, fp32 accumulate, bf16 out. One wave per node.
// ===========================================================================
__global__ __launch_bounds__(256) void agg256b(const unsigned short* __restrict__ h,
                                               const int* __restrict__ offs,
                                               const int* __restrict__ srcs,
                                               unsigned short* __restrict__ outp) {
    int node = blockIdx.x * 4 + (threadIdx.x >> 6);
    int lane = threadIdx.x & 63;
    if (node >= NN) return;
    int beg = offs[node], end = offs[node + 1];
    float a0 = 0, a1 = 0, a2 = 0, a3 = 0;
    float b0 = 0, b1 = 0, b2 = 0, b3 = 0;
    int j = beg;
    for (; j + 2 <= end; j += 2) {
        int s0 = srcs[j], s1 = srcs[j + 1];
        uint2 u = ((const uint2*)(h + (size_t)s0 * 256))[lane];
        uint2 v = ((const uint2*)(h + (size_t)s1 * 256))[lane];
        a0 += bflo(u.x); a1 += bfhi(u.x); a2 += bflo(u.y); a3 += bfhi(u.y);
        b0 += bflo(v.x); b1 += bfhi(v.x); b2 += bflo(v.y); b3 += bfhi(v.y);
    }
    if (j < end) {
        uint2 u = ((const uint2*)(h + (size_t)srcs[j] * 256))[lane];
        a0 += bflo(u.x); a1 += bfhi(u.x); a2 += bflo(u.y); a3 += bfhi(u.y);
    }
    unsigned r0 = rne_bf16(a0 + b0) | (rne_bf16(a1 + b1) << 16);
    unsigned r1 = rne_bf16(a2 + b2) | (rne_bf16(a3 + b3) << 16);
    ((uint2*)(outp + (size_t)node * 256))[lane] = make_uint2(r0, r1);
}

// 16-wide fp32 aggregation (final layer)
__global__ __launch_bounds__(256) void agg16(const float* __restrict__ h,
                                             const int* __restrict__ offs,
                                             const int* __restrict__ srcs,
                                             float* __restrict__ outp) {
    int tid = blockIdx.x * 256 + threadIdx.x;
    int node = tid >> 4, f = tid & 15;
    if (node >= NN) return;
    int beg = offs[node], end = offs[node + 1];
    float acc = 0.f;
    for (int j = beg; j < end; ++j)
        acc += h[(size_t)srcs[j] * 16 + f];
    outp[(size_t)node * 16 + f] = acc;
}

// ===========================================================================
extern "C" void kernel_launch(void* const* d_in, const int* in_sizes, int n_in,
                              void* d_out, int out_size, void* d_ws, size_t ws_size,
                              hipStream_t stream) {
    const float* X   = (const float*)d_in[0];   // [100000, 512]
    const int*   src = (const int*)d_in[1];     // [3200000]
    const int*   dst = (const int*)d_in[2];     // [3200000]
    const float* W1  = (const float*)d_in[3];   // [512, 256]
    const float* W2  = (const float*)d_in[4];   // [256, 256]
    const float* W3  = (const float*)d_in[5];   // [256, 16]
    float* out = (float*)d_out;                 // [100000, 16]

    char* ws = (char*)d_ws;
    unsigned short* Hb  = (unsigned short*)ws;  ws += (size_t)NN * 256 * 2;  // 51.2 MB
    unsigned short* Gb  = (unsigned short*)ws;  ws += (size_t)NN * 256 * 2;  // 51.2 MB
    unsigned short* W1t = (unsigned short*)ws;  ws += (size_t)256 * 512 * 2;
    unsigned short* W2t = (unsigned short*)ws;  ws += (size_t)256 * 256 * 2;
    int* srcs     = (int*)ws;                   ws += (size_t)NE * 4;        // 12.8 MB
    int* offs     = (int*)ws;                   ws += ((size_t)NN + 4) * 4;
    int* cnt      = (int*)ws;                   ws += (size_t)NN * 4;
    int* partials = (int*)ws;                   ws += 512;
    float* H3 = (float*)Hb;   // layer-3 projection [NN,16] fp32, reuses Hb space

    const int edge_blocks = (NE + 255) / 256;
    const int gemm_blocks = (NN + 127) / 128;   // 782

    // ---- CSR build ----
    hipMemsetAsync(cnt, 0, (size_t)NN * 4, stream);
    csr_hist<<<edge_blocks, 256, 0, stream>>>(dst, cnt);
    scan_pass1<<<NCHUNK, 256, 0, stream>>>(cnt, partials);
    scan_pass2<<<1, 64, 0, stream>>>(partials);
    scan_pass3<<<NCHUNK, 256, 0, stream>>>(cnt, partials, offs);
    hipMemsetAsync(cnt, 0, (size_t)NN * 4, stream);
    csr_fill<<<edge_blocks, 256, 0, stream>>>(src, dst, offs, cnt, srcs);

    // ---- weight prep ----
    cvtW<<<512, 256, 0, stream>>>(W1, W1t, 512);
    cvtW<<<256, 256, 0, stream>>>(W2, W2t, 256);

    // ---- Layer 1 ----
    gemm_mfma<512, true><<<gemm_blocks, 512, 0, stream>>>(X, W1t, Hb);
    agg256b<<<(NN + 3) / 4, 256, 0, stream>>>(Hb, offs, srcs, Gb);
    // ---- Layer 2 ----
    gemm_mfma<256, false><<<gemm_blocks, 512, 0, stream>>>(Gb, W2t, Hb);
    agg256b<<<(NN + 3) / 4, 256, 0, stream>>>(Hb, offs, srcs, Gb);
    // ---- Layer 3 ----
    gemm_n16b<<<(NN + 15) / 16, 256, 0, stream>>>(Gb, W3, H3, NN);
    agg16<<<(NN * 16 + 255) / 256, 256, 0, stream>>>(H3, offs, srcs, out);
}

// Round 4
// 549.509 us; speedup vs baseline: 40.8323x; 1.8792x over previous
//
#include <hip/hip_runtime.h>

#define NN 100000
#define NE 3200000
#define NCHUNK 98   // ceil(NN/1024)

typedef short bf16x8 __attribute__((ext_vector_type(8)));
typedef float f32x4  __attribute__((ext_vector_type(4)));

__device__ inline unsigned rne_bf16(float x) {
    unsigned u = __float_as_uint(x);
    return (u + 0x7fffu + ((u >> 16) & 1u)) >> 16;   // round-to-nearest-even
}

// ===========================================================================
// Small fp32 GEMM (round-1 proven): C[M][16] = A[M][256] * B[256][16]
// ===========================================================================
__global__ __launch_bounds__(256) void gemm_n16(const float* __restrict__ A,
                                                const float* __restrict__ B,
                                                float* __restrict__ C, int M) {
    __shared__ float As[16][260];
    __shared__ float Bs[256][16];

    const int t = threadIdx.x;
    const int block_row = blockIdx.x * 16;

    for (int i = t; i < 1024; i += 256)
        ((float4*)&Bs[0][0])[i] = ((const float4*)B)[i];
    for (int i = t; i < 1024; i += 256) {
        int idx = i << 2;
        int r = idx >> 8, c = idx & 255;
        int row = block_row + r;
        float4 v = (row < M) ? ((const float4*)(A + (size_t)row * 256))[c >> 2]
                             : make_float4(0.f, 0.f, 0.f, 0.f);
        *(float4*)&As[r][c] = v;
    }
    __syncthreads();

    const int r = t >> 4, c = t & 15;
    float acc = 0.f;
#pragma unroll 8
    for (int k = 0; k < 256; ++k) acc += As[r][k] * Bs[k][c];

    int row = block_row + r;
    if (row < M) C[(size_t)row * 16 + c] = acc;
}

// transpose+convert C2[512][16] fp32 -> WcT[16][512] bf16
__global__ __launch_bounds__(256) void cvt_wct(const float* __restrict__ C2,
                                               unsigned short* __restrict__ WcT) {
    int id = blockIdx.x * 256 + threadIdx.x;
    if (id < 8192) {
        int r = id >> 4, c = id & 15;
        WcT[c * 512 + r] = (unsigned short)rne_bf16(C2[id]);
    }
}

// ===========================================================================
// Y[100000][16] fp32 = X[100000][512] (fp32, cast bf16) * WcT^T (bf16)
// 512 threads = 8 waves; 128 rows/block; BK=64; one 16x16 frag per wave.
// ===========================================================================
__global__ __launch_bounds__(512) void gemm_xwc(const float* __restrict__ X,
                                                const unsigned short* __restrict__ WcT,
                                                float* __restrict__ Y) {
    __shared__ unsigned short As[128][72];   // 64-wide K chunk, +8 pad
    __shared__ unsigned short Ws[16][520];   // full K=512, +8 pad

    const int t = threadIdx.x;
    const int brow = blockIdx.x * 128;
    const int w = t >> 6, lane = t & 63;
    const int lrow = lane & 15, lk8 = (lane >> 4) * 8;

    // load WcT (16KB) into LDS once: 1024 uint4
    for (int idx = t; idx < 1024; idx += 512) {
        int row = idx >> 6, ch = idx & 63;
        *(uint4*)&Ws[row][ch * 8] = ((const uint4*)(WcT + row * 512))[ch];
    }

    const int s_arow = t & 127, s_aq = t >> 7;   // 4 chunks of 16 halfs per row
    const bool arow_ok = (brow + s_arow) < NN;
    const float* Ap0 = X + (size_t)(brow + s_arow) * 512 + s_aq * 16;

    f32x4 acc = {};

    for (int k0 = 0; k0 < 512; k0 += 64) {
        float4 f[4];
        if (arow_ok) {
            const float4* p = (const float4*)(Ap0 + k0);
#pragma unroll
            for (int i = 0; i < 4; ++i) f[i] = p[i];
        } else {
#pragma unroll
            for (int i = 0; i < 4; ++i) f[i] = make_float4(0.f, 0.f, 0.f, 0.f);
        }
        unsigned p8[8];
#pragma unroll
        for (int i = 0; i < 4; ++i) {
            p8[2 * i]     = rne_bf16(f[i].x) | (rne_bf16(f[i].y) << 16);
            p8[2 * i + 1] = rne_bf16(f[i].z) | (rne_bf16(f[i].w) << 16);
        }
        *(uint4*)&As[s_arow][s_aq * 16]     = make_uint4(p8[0], p8[1], p8[2], p8[3]);
        *(uint4*)&As[s_arow][s_aq * 16 + 8] = make_uint4(p8[4], p8[5], p8[6], p8[7]);
        __syncthreads();

#pragma unroll
        for (int ks = 0; ks < 2; ++ks) {
            bf16x8 af = *(const bf16x8*)&As[w * 16 + lrow][ks * 32 + lk8];
            bf16x8 bw = *(const bf16x8*)&Ws[lrow][k0 + ks * 32 + lk8];
            acc = __builtin_amdgcn_mfma_f32_16x16x32_bf16(af, bw, acc, 0, 0, 0);
        }
        __syncthreads();
    }

    // C/D layout: col = lane&15, row = (lane>>4)*4 + reg
    const int col = lrow;
    const int rbase = brow + w * 16 + (lane >> 4) * 4;
#pragma unroll
    for (int r = 0; r < 4; ++r) {
        int row = rbase + r;
        if (row < NN) Y[(size_t)row * 16 + col] = acc[r];
    }
}

// ===========================================================================
// CSR build (round-2 proven)
// ===========================================================================
__global__ __launch_bounds__(256) void csr_hist(const int* __restrict__ dst,
                                                int* __restrict__ cnt) {
    int e = blockIdx.x * 256 + threadIdx.x;
    if (e < NE) atomicAdd(&cnt[dst[e]], 1);
}

__global__ __launch_bounds__(256) void scan_pass1(const int* __restrict__ cnt,
                                                  int* __restrict__ partials) {
    __shared__ int red[256];
    int b = blockIdx.x, t = threadIdx.x;
    int idx = b * 1024 + t * 4;
    int s = 0;
#pragma unroll
    for (int i = 0; i < 4; ++i)
        if (idx + i < NN) s += cnt[idx + i];
    red[t] = s;
    __syncthreads();
    for (int off = 128; off > 0; off >>= 1) {
        if (t < off) red[t] += red[t + off];
        __syncthreads();
    }
    if (t == 0) partials[b] = red[0];
}

__global__ void scan_pass2(int* partials) {
    if (blockIdx.x == 0 && threadIdx.x == 0) {
        int acc = 0;
        for (int i = 0; i < NCHUNK; ++i) {
            int v = partials[i];
            partials[i] = acc;
            acc += v;
        }
    }
}

__global__ __launch_bounds__(256) void scan_pass3(const int* __restrict__ cnt,
                                                  const int* __restrict__ chunk_pfx,
                                                  int* __restrict__ offs) {
    __shared__ int ts[256];
    int b = blockIdx.x, t = threadIdx.x;
    int base_idx = b * 1024 + t * 4;
    int c[4];
#pragma unroll
    for (int i = 0; i < 4; ++i) {
        int idx = base_idx + i;
        c[i] = (idx < NN) ? cnt[idx] : 0;
    }
    int s = c[0] + c[1] + c[2] + c[3];
    ts[t] = s;
    __syncthreads();
    for (int off = 1; off < 256; off <<= 1) {
        int v = (t >= off) ? ts[t - off] : 0;
        __syncthreads();
        ts[t] += v;
        __syncthreads();
    }
    int run = chunk_pfx[b] + (ts[t] - s);
#pragma unroll
    for (int i = 0; i < 4; ++i) {
        int idx = base_idx + i;
        if (idx < NN) offs[idx] = run;
        run += c[i];
    }
    if (b == 0 && t == 0) offs[NN] = NE;
}

__global__ __launch_bounds__(256) void csr_fill(const int* __restrict__ src,
                                                const int* __restrict__ dst,
                                                const int* __restrict__ offs,
                                                int* __restrict__ cursor,
                                                int* __restrict__ srcs) {
    int e = blockIdx.x * 256 + threadIdx.x;
    if (e >= NE) return;
    int d = dst[e];
    int pos = offs[d] + atomicAdd(&cursor[d], 1);
    srcs[pos] = src[e];
}

// ===========================================================================
// Width-16 fp32 gather aggregation: 16 threads per node
// ===========================================================================
__global__ __launch_bounds__(256) void agg16(const float* __restrict__ h,
                                             const int* __restrict__ offs,
                                             const int* __restrict__ srcs,
                                             float* __restrict__ outp) {
    int tid = blockIdx.x * 256 + threadIdx.x;
    int node = tid >> 4, f = tid & 15;
    if (node >= NN) return;
    int beg = offs[node], end = offs[node + 1];
    float a = 0.f, b = 0.f;
    int j = beg;
    for (; j + 2 <= end; j += 2) {
        int s0 = srcs[j], s1 = srcs[j + 1];
        a += h[(size_t)s0 * 16 + f];
        b += h[(size_t)s1 * 16 + f];
    }
    if (j < end) a += h[(size_t)srcs[j] * 16 + f];
    outp[(size_t)node * 16 + f] = a + b;
}

// ===========================================================================
extern "C" void kernel_launch(void* const* d_in, const int* in_sizes, int n_in,
                              void* d_out, int out_size, void* d_ws, size_t ws_size,
                              hipStream_t stream) {
    const float* X   = (const float*)d_in[0];   // [100000, 512]
    const int*   src = (const int*)d_in[1];     // [3200000]
    const int*   dst = (const int*)d_in[2];     // [3200000]
    const float* W1  = (const float*)d_in[3];   // [512, 256]
    const float* W2  = (const float*)d_in[4];   // [256, 256]
    const float* W3  = (const float*)d_in[5];   // [256, 16]
    float* out = (float*)d_out;                 // [100000, 16]

    char* ws = (char*)d_ws;
    float* Y  = (float*)ws;                     ws += (size_t)NN * 16 * 4;   // 6.4 MB
    float* G  = (float*)ws;                     ws += (size_t)NN * 16 * 4;   // 6.4 MB
    float* M1 = (float*)ws;                     ws += 256 * 16 * 4;          // W2@W3
    float* C2 = (float*)ws;                     ws += 512 * 16 * 4;          // W1@M1
    unsigned short* WcT = (unsigned short*)ws;  ws += 16 * 512 * 2;          // bf16 [16][512]
    int* srcs     = (int*)ws;                   ws += (size_t)NE * 4;        // 12.8 MB
    int* offs     = (int*)ws;                   ws += ((size_t)NN + 4) * 4;
    int* cnt      = (int*)ws;                   ws += (size_t)NN * 4;
    int* partials = (int*)ws;                   ws += 512;

    const int edge_blocks = (NE + 255) / 256;   // 12500

    // ---- weight chain: Wc = W1 @ (W2 @ W3), stored transposed bf16 ----
    gemm_n16<<<16, 256, 0, stream>>>(W2, W3, M1, 256);
    gemm_n16<<<32, 256, 0, stream>>>(W1, M1, C2, 512);
    cvt_wct<<<32, 256, 0, stream>>>(C2, WcT);

    // ---- single projection: Y = X @ Wc (reads X exactly once) ----
    gemm_xwc<<<(NN + 127) / 128, 512, 0, stream>>>(X, WcT, Y);

    // ---- CSR build ----
    hipMemsetAsync(cnt, 0, (size_t)NN * 4, stream);
    csr_hist<<<edge_blocks, 256, 0, stream>>>(dst, cnt);
    scan_pass1<<<NCHUNK, 256, 0, stream>>>(cnt, partials);
    scan_pass2<<<1, 64, 0, stream>>>(partials);
    scan_pass3<<<NCHUNK, 256, 0, stream>>>(cnt, partials, offs);
    hipMemsetAsync(cnt, 0, (size_t)NN * 4, stream);
    csr_fill<<<edge_blocks, 256, 0, stream>>>(src, dst, offs, cnt, srcs);

    // ---- out = A^3 Y : three width-16 fp32 aggregations ----
    const int agg_blocks = (NN * 16 + 255) / 256;   // 6250
    agg16<<<agg_blocks, 256, 0, stream>>>(Y, offs, srcs, G);
    agg16<<<agg_blocks, 256, 0, stream>>>(G, offs, srcs, Y);
    agg16<<<agg_blocks, 256, 0, stream>>>(Y, offs, srcs, out);
}

// Round 5
// 543.347 us; speedup vs baseline: 41.2953x; 1.0113x over previous
//
#include <hip/hip_runtime.h>

#define NN 100000
#define NE 3200000
#define NPART 8
#define NTOT (NPART * NN)          // 800000 CSR keys (part-major)
#define NCHUNK2 ((NTOT + 1023) / 1024)   // 782

typedef short bf16x8 __attribute__((ext_vector_type(8)));
typedef float f32x4  __attribute__((ext_vector_type(4)));

__device__ inline unsigned rne_bf16(float x) {
    unsigned u = __float_as_uint(x);
    return (u + 0x7fffu + ((u >> 16) & 1u)) >> 16;   // round-to-nearest-even
}
__device__ inline float bflo(unsigned u) { return __uint_as_float(u << 16); }
__device__ inline float bfhi(unsigned u) { return __uint_as_float(u & 0xffff0000u); }

// ===========================================================================
// Small fp32 GEMM: C[M][16] = A[M][256] * B[256][16]  (weight chain)
// ===========================================================================
__global__ __launch_bounds__(256) void gemm_n16(const float* __restrict__ A,
                                                const float* __restrict__ B,
                                                float* __restrict__ C, int M) {
    __shared__ float As[16][260];
    __shared__ float Bs[256][16];

    const int t = threadIdx.x;
    const int block_row = blockIdx.x * 16;

    for (int i = t; i < 1024; i += 256)
        ((float4*)&Bs[0][0])[i] = ((const float4*)B)[i];
    for (int i = t; i < 1024; i += 256) {
        int idx = i << 2;
        int r = idx >> 8, c = idx & 255;
        int row = block_row + r;
        float4 v = (row < M) ? ((const float4*)(A + (size_t)row * 256))[c >> 2]
                             : make_float4(0.f, 0.f, 0.f, 0.f);
        *(float4*)&As[r][c] = v;
    }
    __syncthreads();

    const int r = t >> 4, c = t & 15;
    float acc = 0.f;
#pragma unroll 8
    for (int k = 0; k < 256; ++k) acc += As[r][k] * Bs[k][c];

    int row = block_row + r;
    if (row < M) C[(size_t)row * 16 + c] = acc;
}

// transpose+convert C2[512][16] fp32 -> WcT[16][512] bf16
__global__ __launch_bounds__(256) void cvt_wct(const float* __restrict__ C2,
                                               unsigned short* __restrict__ WcT) {
    int id = blockIdx.x * 256 + threadIdx.x;
    if (id < 8192) {
        int r = id >> 4, c = id & 15;
        WcT[c * 512 + r] = (unsigned short)rne_bf16(C2[id]);
    }
}

// ===========================================================================
// Yb[100000][16] bf16 = X[100000][512] (fp32, cast bf16) * WcT^T (bf16)
// ===========================================================================
__global__ __launch_bounds__(512) void gemm_xwc(const float* __restrict__ X,
                                                const unsigned short* __restrict__ WcT,
                                                unsigned short* __restrict__ Yb) {
    __shared__ unsigned short As[128][72];
    __shared__ unsigned short Ws[16][520];

    const int t = threadIdx.x;
    const int brow = blockIdx.x * 128;
    const int w = t >> 6, lane = t & 63;
    const int lrow = lane & 15, lk8 = (lane >> 4) * 8;

    for (int idx = t; idx < 1024; idx += 512) {
        int row = idx >> 6, ch = idx & 63;
        *(uint4*)&Ws[row][ch * 8] = ((const uint4*)(WcT + row * 512))[ch];
    }

    const int s_arow = t & 127, s_aq = t >> 7;
    const bool arow_ok = (brow + s_arow) < NN;
    const float* Ap0 = X + (size_t)(brow + s_arow) * 512 + s_aq * 16;

    f32x4 acc = {};

    for (int k0 = 0; k0 < 512; k0 += 64) {
        float4 f[4];
        if (arow_ok) {
            const float4* p = (const float4*)(Ap0 + k0);
#pragma unroll
            for (int i = 0; i < 4; ++i) f[i] = p[i];
        } else {
#pragma unroll
            for (int i = 0; i < 4; ++i) f[i] = make_float4(0.f, 0.f, 0.f, 0.f);
        }
        unsigned p8[8];
#pragma unroll
        for (int i = 0; i < 4; ++i) {
            p8[2 * i]     = rne_bf16(f[i].x) | (rne_bf16(f[i].y) << 16);
            p8[2 * i + 1] = rne_bf16(f[i].z) | (rne_bf16(f[i].w) << 16);
        }
        *(uint4*)&As[s_arow][s_aq * 16]     = make_uint4(p8[0], p8[1], p8[2], p8[3]);
        *(uint4*)&As[s_arow][s_aq * 16 + 8] = make_uint4(p8[4], p8[5], p8[6], p8[7]);
        __syncthreads();

#pragma unroll
        for (int ks = 0; ks < 2; ++ks) {
            bf16x8 af = *(const bf16x8*)&As[w * 16 + lrow][ks * 32 + lk8];
            bf16x8 bw = *(const bf16x8*)&Ws[lrow][k0 + ks * 32 + lk8];
            acc = __builtin_amdgcn_mfma_f32_16x16x32_bf16(af, bw, acc, 0, 0, 0);
        }
        __syncthreads();
    }

    const int col = lrow;
    const int rbase = brow + w * 16 + (lane >> 4) * 4;
#pragma unroll
    for (int r = 0; r < 4; ++r) {
        int row = rbase + r;
        if (row < NN)
            Yb[(size_t)row * 16 + col] = (unsigned short)rne_bf16(acc[r]);
    }
}

// ===========================================================================
// CSR build, part-major keys: key = (blockIdx&7)*NN + dst[e]
// ===========================================================================
__global__ __launch_bounds__(256) void csr_hist(const int* __restrict__ dst,
                                                int* __restrict__ cnt) {
    int b = blockIdx.x;
    int e = b * 256 + threadIdx.x;
    if (e < NE) atomicAdd(&cnt[(b & 7) * NN + dst[e]], 1);
}

// pass1: per-1024-chunk sums over NTOT keys
__global__ __launch_bounds__(256) void scan_pass1(const int* __restrict__ cnt,
                                                  int* __restrict__ partials) {
    __shared__ int red[256];
    int b = blockIdx.x, t = threadIdx.x;
    int idx = b * 1024 + t * 4;
    int s = 0;
#pragma unroll
    for (int i = 0; i < 4; ++i)
        if (idx + i < NTOT) s += cnt[idx + i];
    red[t] = s;
    __syncthreads();
    for (int off = 128; off > 0; off >>= 1) {
        if (t < off) red[t] += red[t + off];
        __syncthreads();
    }
    if (t == 0) partials[b] = red[0];
}

// pass2: single-block parallel exclusive scan of NCHUNK2 partials
__global__ __launch_bounds__(1024) void scan_pass2(int* partials) {
    __shared__ int s[1024];
    int t = threadIdx.x;
    int v = (t < NCHUNK2) ? partials[t] : 0;
    s[t] = v;
    __syncthreads();
    for (int off = 1; off < 1024; off <<= 1) {
        int u = (t >= off) ? s[t - off] : 0;
        __syncthreads();
        s[t] += u;
        __syncthreads();
    }
    if (t < NCHUNK2) partials[t] = s[t] - v;   // exclusive
}

// pass3: per-chunk exclusive scan + chunk base -> offs; offs[NTOT] = NE
__global__ __launch_bounds__(256) void scan_pass3(const int* __restrict__ cnt,
                                                  const int* __restrict__ chunk_pfx,
                                                  int* __restrict__ offs) {
    __shared__ int ts[256];
    int b = blockIdx.x, t = threadIdx.x;
    int base_idx = b * 1024 + t * 4;
    int c[4];
#pragma unroll
    for (int i = 0; i < 4; ++i) {
        int idx = base_idx + i;
        c[i] = (idx < NTOT) ? cnt[idx] : 0;
    }
    int s = c[0] + c[1] + c[2] + c[3];
    ts[t] = s;
    __syncthreads();
    for (int off = 1; off < 256; off <<= 1) {
        int v = (t >= off) ? ts[t - off] : 0;
        __syncthreads();
        ts[t] += v;
        __syncthreads();
    }
    int run = chunk_pfx[b] + (ts[t] - s);
#pragma unroll
    for (int i = 0; i < 4; ++i) {
        int idx = base_idx + i;
        if (idx < NTOT) offs[idx] = run;
        run += c[i];
    }
    if (b == 0 && t == 0) offs[NTOT] = NE;
}

// cursor pre-initialized to offs (D2D copy) -> atomicAdd returns position
__global__ __launch_bounds__(256) void csr_fill(const int* __restrict__ src,
                                                const int* __restrict__ dst,
                                                int* __restrict__ cursor,
                                                int* __restrict__ srcs) {
    int b = blockIdx.x;
    int e = b * 256 + threadIdx.x;
    if (e >= NE) return;
    int key = (b & 7) * NN + dst[e];
    int pos = atomicAdd(&cursor[key], 1);
    srcs[pos] = src[e];
}

// ===========================================================================
// Aggregation over 8 part-sublists: bf16 gather, fp32 accumulate.
// 8 threads per node, 2 features each (uint = 2xbf16 loads).
// ===========================================================================
template<bool OUT_F32>
__global__ __launch_bounds__(256) void agg16b(const unsigned short* __restrict__ h,
                                              const int* __restrict__ offs,
                                              const int* __restrict__ srcs,
                                              void* __restrict__ outp) {
    int tid = blockIdx.x * 256 + threadIdx.x;
    int node = tid >> 3, f2 = tid & 7;
    if (node >= NN) return;
    float a0 = 0, a1 = 0, b0 = 0, b1 = 0;
#pragma unroll
    for (int p = 0; p < NPART; ++p) {
        int beg = offs[p * NN + node];
        int end = offs[p * NN + node + 1];   // contiguous keys -> valid end
        int j = beg;
        for (; j + 2 <= end; j += 2) {
            int s0 = srcs[j], s1 = srcs[j + 1];
            unsigned u = *(const unsigned*)(h + (size_t)s0 * 16 + f2 * 2);
            unsigned v = *(const unsigned*)(h + (size_t)s1 * 16 + f2 * 2);
            a0 += bflo(u); a1 += bfhi(u);
            b0 += bflo(v); b1 += bfhi(v);
        }
        if (j < end) {
            unsigned u = *(const unsigned*)(h + (size_t)srcs[j] * 16 + f2 * 2);
            a0 += bflo(u); a1 += bfhi(u);
        }
    }
    float r0 = a0 + b0, r1 = a1 + b1;
    if (OUT_F32) {
        ((float2*)outp)[(size_t)node * 8 + f2] = make_float2(r0, r1);
    } else {
        unsigned r = rne_bf16(r0) | (rne_bf16(r1) << 16);
        ((unsigned*)outp)[(size_t)node * 8 + f2] = r;
    }
}

// ===========================================================================
extern "C" void kernel_launch(void* const* d_in, const int* in_sizes, int n_in,
                              void* d_out, int out_size, void* d_ws, size_t ws_size,
                              hipStream_t stream) {
    const float* X   = (const float*)d_in[0];   // [100000, 512]
    const int*   src = (const int*)d_in[1];     // [3200000]
    const int*   dst = (const int*)d_in[2];     // [3200000]
    const float* W1  = (const float*)d_in[3];   // [512, 256]
    const float* W2  = (const float*)d_in[4];   // [256, 256]
    const float* W3  = (const float*)d_in[5];   // [256, 16]
    float* out = (float*)d_out;                 // [100000, 16]

    char* ws = (char*)d_ws;
    unsigned short* Yb = (unsigned short*)ws;   ws += (size_t)NN * 16 * 2;   // 3.2 MB
    unsigned short* Gb = (unsigned short*)ws;   ws += (size_t)NN * 16 * 2;   // 3.2 MB
    float* M1 = (float*)ws;                     ws += 256 * 16 * 4;
    float* C2 = (float*)ws;                     ws += 512 * 16 * 4;
    unsigned short* WcT = (unsigned short*)ws;  ws += 16 * 512 * 2;
    int* srcs     = (int*)ws;                   ws += (size_t)NE * 4;        // 12.8 MB
    int* offs     = (int*)ws;                   ws += ((size_t)NTOT + 4) * 4;// 3.2 MB
    int* cnt      = (int*)ws;                   ws += (size_t)NTOT * 4;      // 3.2 MB
    int* cursor   = (int*)ws;                   ws += (size_t)NTOT * 4;      // 3.2 MB
    int* partials = (int*)ws;                   ws += 4096;

    const int edge_blocks = (NE + 255) / 256;   // 12500

    // ---- weight chain: Wc = W1 @ (W2 @ W3) -> bf16 [16][512] ----
    gemm_n16<<<16, 256, 0, stream>>>(W2, W3, M1, 256);
    gemm_n16<<<32, 256, 0, stream>>>(W1, M1, C2, 512);
    cvt_wct<<<32, 256, 0, stream>>>(C2, WcT);

    // ---- single projection: Yb = bf16(X @ Wc) ----
    gemm_xwc<<<(NN + 127) / 128, 512, 0, stream>>>(X, WcT, Yb);

    // ---- CSR build, part-major (XCD-local writes) ----
    hipMemsetAsync(cnt, 0, (size_t)NTOT * 4, stream);
    csr_hist<<<edge_blocks, 256, 0, stream>>>(dst, cnt);
    scan_pass1<<<NCHUNK2, 256, 0, stream>>>(cnt, partials);
    scan_pass2<<<1, 1024, 0, stream>>>(partials);
    scan_pass3<<<NCHUNK2, 256, 0, stream>>>(cnt, partials, offs);
    hipMemcpyAsync(cursor, offs, (size_t)NTOT * 4, hipMemcpyDeviceToDevice, stream);
    csr_fill<<<edge_blocks, 256, 0, stream>>>(src, dst, cursor, srcs);

    // ---- out = A^3 Y : three width-16 aggregations (bf16,bf16,fp32-out) ----
    const int agg_blocks = (NN * 8 + 255) / 256;   // 3125
    agg16b<false><<<agg_blocks, 256, 0, stream>>>(Yb, offs, srcs, Gb);
    agg16b<false><<<agg_blocks, 256, 0, stream>>>(Gb, offs, srcs, Yb);
    agg16b<true><<<agg_blocks, 256, 0, stream>>>(Yb, offs, srcs, out);
}

// Round 6
// 248.347 us; speedup vs baseline: 90.3482x; 2.1879x over previous
//
#include <hip/hip_runtime.h>

#define NN 100000
#define NE 3200000
#define NBUCK 196                  // ceil(100000/512) buckets of 512 dst nodes

typedef short bf16x8 __attribute__((ext_vector_type(8)));
typedef float f32x4  __attribute__((ext_vector_type(4)));

__device__ inline unsigned rne_bf16(float x) {
    unsigned u = __float_as_uint(x);
    return (u + 0x7fffu + ((u >> 16) & 1u)) >> 16;   // round-to-nearest-even
}
__device__ inline float bflo(unsigned u) { return __uint_as_float(u << 16); }
__device__ inline float bfhi(unsigned u) { return __uint_as_float(u & 0xffff0000u); }

// ===========================================================================
// Small fp32 GEMM: C[M][16] = A[M][256] * B[256][16]  (weight chain)
// ===========================================================================
__global__ __launch_bounds__(256) void gemm_n16(const float* __restrict__ A,
                                                const float* __restrict__ B,
                                                float* __restrict__ C, int M) {
    __shared__ float As[16][260];
    __shared__ float Bs[256][16];

    const int t = threadIdx.x;
    const int block_row = blockIdx.x * 16;

    for (int i = t; i < 1024; i += 256)
        ((float4*)&Bs[0][0])[i] = ((const float4*)B)[i];
    for (int i = t; i < 1024; i += 256) {
        int idx = i << 2;
        int r = idx >> 8, c = idx & 255;
        int row = block_row + r;
        float4 v = (row < M) ? ((const float4*)(A + (size_t)row * 256))[c >> 2]
                             : make_float4(0.f, 0.f, 0.f, 0.f);
        *(float4*)&As[r][c] = v;
    }
    __syncthreads();

    const int r = t >> 4, c = t & 15;
    float acc = 0.f;
#pragma unroll 8
    for (int k = 0; k < 256; ++k) acc += As[r][k] * Bs[k][c];

    int row = block_row + r;
    if (row < M) C[(size_t)row * 16 + c] = acc;
}

// transpose+convert C2[512][16] fp32 -> WcT[16][512] bf16
__global__ __launch_bounds__(256) void cvt_wct(const float* __restrict__ C2,
                                               unsigned short* __restrict__ WcT) {
    int id = blockIdx.x * 256 + threadIdx.x;
    if (id < 8192) {
        int r = id >> 4, c = id & 15;
        WcT[c * 512 + r] = (unsigned short)rne_bf16(C2[id]);
    }
}

// ===========================================================================
// Yb[100000][16] bf16 = X[100000][512] (fp32, cast bf16) * WcT^T (bf16)
// ===========================================================================
__global__ __launch_bounds__(512) void gemm_xwc(const float* __restrict__ X,
                                                const unsigned short* __restrict__ WcT,
                                                unsigned short* __restrict__ Yb) {
    __shared__ unsigned short As[128][72];
    __shared__ unsigned short Ws[16][520];

    const int t = threadIdx.x;
    const int brow = blockIdx.x * 128;
    const int w = t >> 6, lane = t & 63;
    const int lrow = lane & 15, lk8 = (lane >> 4) * 8;

    for (int idx = t; idx < 1024; idx += 512) {
        int row = idx >> 6, ch = idx & 63;
        *(uint4*)&Ws[row][ch * 8] = ((const uint4*)(WcT + row * 512))[ch];
    }

    const int s_arow = t & 127, s_aq = t >> 7;
    const bool arow_ok = (brow + s_arow) < NN;
    const float* Ap0 = X + (size_t)(brow + s_arow) * 512 + s_aq * 16;

    f32x4 acc = {};

    for (int k0 = 0; k0 < 512; k0 += 64) {
        float4 f[4];
        if (arow_ok) {
            const float4* p = (const float4*)(Ap0 + k0);
#pragma unroll
            for (int i = 0; i < 4; ++i) f[i] = p[i];
        } else {
#pragma unroll
            for (int i = 0; i < 4; ++i) f[i] = make_float4(0.f, 0.f, 0.f, 0.f);
        }
        unsigned p8[8];
#pragma unroll
        for (int i = 0; i < 4; ++i) {
            p8[2 * i]     = rne_bf16(f[i].x) | (rne_bf16(f[i].y) << 16);
            p8[2 * i + 1] = rne_bf16(f[i].z) | (rne_bf16(f[i].w) << 16);
        }
        *(uint4*)&As[s_arow][s_aq * 16]     = make_uint4(p8[0], p8[1], p8[2], p8[3]);
        *(uint4*)&As[s_arow][s_aq * 16 + 8] = make_uint4(p8[4], p8[5], p8[6], p8[7]);
        __syncthreads();

#pragma unroll
        for (int ks = 0; ks < 2; ++ks) {
            bf16x8 af = *(const bf16x8*)&As[w * 16 + lrow][ks * 32 + lk8];
            bf16x8 bw = *(const bf16x8*)&Ws[lrow][k0 + ks * 32 + lk8];
            acc = __builtin_amdgcn_mfma_f32_16x16x32_bf16(af, bw, acc, 0, 0, 0);
        }
        __syncthreads();
    }

    const int col = lrow;
    const int rbase = brow + w * 16 + (lane >> 4) * 4;
#pragma unroll
    for (int r = 0; r < 4; ++r) {
        int row = rbase + r;
        if (row < NN)
            Yb[(size_t)row * 16 + col] = (unsigned short)rne_bf16(acc[r]);
    }
}

// ===========================================================================
// CSR build via 2-level binning
// ===========================================================================
// coarse histogram of dst>>9 (196 buckets), LDS-reduced
__global__ __launch_bounds__(256) void hist_coarse(const int* __restrict__ dst,
                                                   int* __restrict__ cntA) {
    __shared__ int h[NBUCK];
    int t = threadIdx.x;
    for (int i = t; i < NBUCK; i += 256) h[i] = 0;
    __syncthreads();
    for (int e = blockIdx.x * 256 + t; e < NE; e += 256 * 256)
        atomicAdd(&h[dst[e] >> 9], 1);
    __syncthreads();
    for (int i = t; i < NBUCK; i += 256)
        if (h[i]) atomicAdd(&cntA[i], h[i]);
}

// exclusive scan of 196 counts -> bucketBase[197]; init cursorA; offs[NN]=NE
__global__ __launch_bounds__(256) void scan_coarse(const int* __restrict__ cntA,
                                                   int* __restrict__ bucketBase,
                                                   int* __restrict__ cursorA,
                                                   int* __restrict__ offs) {
    __shared__ int s[256];
    int t = threadIdx.x;
    int v = (t < NBUCK) ? cntA[t] : 0;
    s[t] = v;
    __syncthreads();
    for (int off = 1; off < 256; off <<= 1) {
        int u = (t >= off) ? s[t - off] : 0;
        __syncthreads();
        s[t] += u;
        __syncthreads();
    }
    int excl = s[t] - v;
    if (t < NBUCK) { bucketBase[t] = excl; cursorA[t] = excl; }
    if (t == 0) { bucketBase[NBUCK] = NE; offs[NN] = NE; }
}

// binA: group edges by coarse bucket; packed val = (src<<9)|(dst&511)
__global__ __launch_bounds__(256) void binA(const int* __restrict__ src,
                                            const int* __restrict__ dst,
                                            int* __restrict__ cursorA,
                                            unsigned* __restrict__ packed) {
    __shared__ int hist[NBUCK];
    int t = threadIdx.x;
    for (int i = t; i < NBUCK; i += 256) hist[i] = 0;
    __syncthreads();

    const int e0 = (blockIdx.x * 256 + t) * 16;
    unsigned val[16];
    short bk[16];
    if (e0 + 15 < NE) {
        int4 sv[4], dv[4];
        const int4* sp = (const int4*)(src + e0);
        const int4* dp = (const int4*)(dst + e0);
#pragma unroll
        for (int i = 0; i < 4; ++i) { sv[i] = sp[i]; dv[i] = dp[i]; }
        const int* s4 = (const int*)sv;
        const int* d4 = (const int*)dv;
#pragma unroll
        for (int i = 0; i < 16; ++i) {
            val[i] = ((unsigned)s4[i] << 9) | (unsigned)(d4[i] & 511);
            bk[i] = (short)(d4[i] >> 9);
        }
    } else {
#pragma unroll
        for (int i = 0; i < 16; ++i) {
            int e = e0 + i;
            if (e < NE) {
                int s = src[e], d = dst[e];
                val[i] = ((unsigned)s << 9) | (unsigned)(d & 511);
                bk[i] = (short)(d >> 9);
            } else bk[i] = -1;
        }
    }
#pragma unroll
    for (int i = 0; i < 16; ++i)
        if (bk[i] >= 0) atomicAdd(&hist[bk[i]], 1);
    __syncthreads();
    // allocate per-block runs in each bucket; hist becomes running cursor
    for (int i = t; i < NBUCK; i += 256) {
        int c = hist[i];
        hist[i] = c ? atomicAdd(&cursorA[i], c) : 0;
    }
    __syncthreads();
#pragma unroll
    for (int i = 0; i < 16; ++i) {
        if (bk[i] >= 0) {
            int pos = atomicAdd(&hist[bk[i]], 1);
            packed[pos] = val[i];
        }
    }
}

// binB: one block per bucket; build offs + scatter srcs within L2-resident region
__global__ __launch_bounds__(512) void binB(const unsigned* __restrict__ packed,
                                            const int* __restrict__ bucketBase,
                                            int* __restrict__ offs,
                                            int* __restrict__ srcs) {
    __shared__ int h[512];
    __shared__ int run[512];
    const int b = blockIdx.x, t = threadIdx.x;
    const int lo = bucketBase[b], hi = bucketBase[b + 1];

    h[t] = 0;
    __syncthreads();
    for (int i = lo + t; i < hi; i += 512)
        atomicAdd(&h[packed[i] & 511], 1);
    __syncthreads();
    int mine = h[t];
    for (int off = 1; off < 512; off <<= 1) {
        int u = (t >= off) ? h[t - off] : 0;
        __syncthreads();
        h[t] += u;
        __syncthreads();
    }
    int gbase = lo + (h[t] - mine);   // exclusive prefix within bucket
    int node = b * 512 + t;
    if (node < NN) offs[node] = gbase;
    run[t] = gbase;
    __syncthreads();
    for (int i = lo + t; i < hi; i += 512) {
        unsigned v = packed[i];
        int pos = atomicAdd(&run[v & 511], 1);
        srcs[pos] = (int)(v >> 9);
    }
}

// ===========================================================================
// Aggregation: bf16 gather, fp32 accumulate; 8 threads/node, 2 feats each
// ===========================================================================
template<bool OUT_F32>
__global__ __launch_bounds__(256) void agg16b(const unsigned short* __restrict__ h,
                                              const int* __restrict__ offs,
                                              const int* __restrict__ srcs,
                                              void* __restrict__ outp) {
    int tid = blockIdx.x * 256 + threadIdx.x;
    int node = tid >> 3, f2 = tid & 7;
    if (node >= NN) return;
    int beg = offs[node], end = offs[node + 1];
    float a0 = 0, a1 = 0, b0 = 0, b1 = 0;
    int j = beg;
    for (; j + 2 <= end; j += 2) {
        int s0 = srcs[j], s1 = srcs[j + 1];
        unsigned u = *(const unsigned*)(h + (size_t)s0 * 16 + f2 * 2);
        unsigned v = *(const unsigned*)(h + (size_t)s1 * 16 + f2 * 2);
        a0 += bflo(u); a1 += bfhi(u);
        b0 += bflo(v); b1 += bfhi(v);
    }
    if (j < end) {
        unsigned u = *(const unsigned*)(h + (size_t)srcs[j] * 16 + f2 * 2);
        a0 += bflo(u); a1 += bfhi(u);
    }
    float r0 = a0 + b0, r1 = a1 + b1;
    if (OUT_F32) {
        ((float2*)outp)[(size_t)node * 8 + f2] = make_float2(r0, r1);
    } else {
        unsigned r = rne_bf16(r0) | (rne_bf16(r1) << 16);
        ((unsigned*)outp)[(size_t)node * 8 + f2] = r;
    }
}

// ===========================================================================
extern "C" void kernel_launch(void* const* d_in, const int* in_sizes, int n_in,
                              void* d_out, int out_size, void* d_ws, size_t ws_size,
                              hipStream_t stream) {
    const float* X   = (const float*)d_in[0];   // [100000, 512]
    const int*   src = (const int*)d_in[1];     // [3200000]
    const int*   dst = (const int*)d_in[2];     // [3200000]
    const float* W1  = (const float*)d_in[3];   // [512, 256]
    const float* W2  = (const float*)d_in[4];   // [256, 256]
    const float* W3  = (const float*)d_in[5];   // [256, 16]
    float* out = (float*)d_out;                 // [100000, 16]

    char* ws = (char*)d_ws;
    unsigned short* Yb = (unsigned short*)ws;   ws += (size_t)NN * 16 * 2;   // 3.2 MB
    unsigned short* Gb = (unsigned short*)ws;   ws += (size_t)NN * 16 * 2;   // 3.2 MB
    float* M1 = (float*)ws;                     ws += 256 * 16 * 4;
    float* C2 = (float*)ws;                     ws += 512 * 16 * 4;
    unsigned short* WcT = (unsigned short*)ws;  ws += 16 * 512 * 2;
    int* srcs       = (int*)ws;                 ws += (size_t)NE * 4;        // 12.8 MB
    unsigned* packed= (unsigned*)ws;            ws += (size_t)NE * 4;        // 12.8 MB
    int* offs       = (int*)ws;                 ws += ((size_t)NN + 4) * 4;  // 400 KB
    int* cntA       = (int*)ws;                 ws += 256 * 4;
    int* bucketBase = (int*)ws;                 ws += 256 * 4;
    int* cursorA    = (int*)ws;                 ws += 256 * 4;

    // ---- weight chain: Wc = W1 @ (W2 @ W3) -> bf16 [16][512] ----
    gemm_n16<<<16, 256, 0, stream>>>(W2, W3, M1, 256);
    gemm_n16<<<32, 256, 0, stream>>>(W1, M1, C2, 512);
    cvt_wct<<<32, 256, 0, stream>>>(C2, WcT);

    // ---- single projection: Yb = bf16(X @ Wc) ----
    gemm_xwc<<<(NN + 127) / 128, 512, 0, stream>>>(X, WcT, Yb);

    // ---- CSR build: coarse hist -> scan -> binA -> binB ----
    hipMemsetAsync(cntA, 0, NBUCK * 4, stream);
    hist_coarse<<<256, 256, 0, stream>>>(dst, cntA);
    scan_coarse<<<1, 256, 0, stream>>>(cntA, bucketBase, cursorA, offs);
    binA<<<(NE + 4095) / 4096, 256, 0, stream>>>(src, dst, cursorA, packed);
    binB<<<NBUCK, 512, 0, stream>>>(packed, bucketBase, offs, srcs);

    // ---- out = A^3 Y : three width-16 aggregations (bf16,bf16,fp32-out) ----
    const int agg_blocks = (NN * 8 + 255) / 256;   // 3125
    agg16b<false><<<agg_blocks, 256, 0, stream>>>(Yb, offs, srcs, Gb);
    agg16b<false><<<agg_blocks, 256, 0, stream>>>(Gb, offs, srcs, Yb);
    agg16b<true><<<agg_blocks, 256, 0, stream>>>(Yb, offs, srcs, out);
}